// Round 1
// baseline (406.100 us; speedup 1.0000x reference)
//
#include <hip/hip_runtime.h>
#include <hip/hip_bf16.h>
#include <cstdint>

typedef unsigned short u16;
typedef __attribute__((ext_vector_type(8))) short bf16x8;
typedef __attribute__((ext_vector_type(4))) float f32x4;

#define BATCH 4
#define CDIM 256
#define NTOK 4096   // H*W

__device__ inline u16 f2bf(float f) {
  union { float f; uint32_t u; } un; un.f = f;
  uint32_t u = un.u;
  u += 0x7fffu + ((u >> 16) & 1u);
  return (u16)(u >> 16);
}
__device__ inline float bf2f(u16 h) {
  union { uint32_t u; float f; } un; un.u = ((uint32_t)h) << 16; return un.f;
}

// ---------------------------------------------------------------------------
// LayerNorm: x [B, C, N] (channel-strided per token) -> xn bf16 [B*N, C]
// Stage a 32-token x 256-channel tile through LDS so both the global read
// (contiguous in n) and the global write (contiguous in c) are coalesced.
// ---------------------------------------------------------------------------
__global__ __launch_bounds__(256) void ln_kernel(const float* __restrict__ x,
                                                 const float* __restrict__ gamma,
                                                 const float* __restrict__ beta,
                                                 u16* __restrict__ xn) {
  __shared__ float tile[CDIM][33];   // [c][token], pad -> bank-conflict-free
  __shared__ float reds[8][32];
  __shared__ float reds2[8][32];
  __shared__ float mu_s[32], rs_s[32];

  int b  = blockIdx.x >> 7;          // 128 blocks per batch (4096/32)
  int n0 = (blockIdx.x & 127) * 32;
  const float* xb = x + (size_t)b * CDIM * NTOK;

  int t = threadIdx.x & 31;   // token within tile
  int g = threadIdx.x >> 5;   // 0..7

  for (int c = g; c < CDIM; c += 8)
    tile[c][t] = xb[(size_t)c * NTOK + n0 + t];
  __syncthreads();

  float s = 0.f, s2 = 0.f;
  for (int c = g * 32; c < g * 32 + 32; ++c) {
    float v = tile[c][t];
    s += v; s2 += v * v;
  }
  reds[g][t] = s; reds2[g][t] = s2;
  __syncthreads();
  if (threadIdx.x < 32) {
    float ts = 0.f, ts2 = 0.f;
    for (int gg = 0; gg < 8; ++gg) { ts += reds[gg][threadIdx.x]; ts2 += reds2[gg][threadIdx.x]; }
    float mu = ts / CDIM;
    float var = ts2 / CDIM - mu * mu;
    mu_s[threadIdx.x] = mu;
    rs_s[threadIdx.x] = rsqrtf(var + 1e-5f);
  }
  __syncthreads();

  int c = threadIdx.x;
  float gam = gamma[c], bet = beta[c];
  u16* out = xn + ((size_t)b * NTOK + n0) * CDIM;
  for (int tt = 0; tt < 32; ++tt) {
    float v = tile[c][tt];
    float y = (v - mu_s[tt]) * rs_s[tt] * gam + bet;
    out[(size_t)tt * CDIM + c] = f2bf(y);
  }
}

// ---------------------------------------------------------------------------
// W [K=256, Cout=256] fp32 -> WT bf16 [Cout, K] (so GEMM B-operand rows are
// contiguous in k)
// ---------------------------------------------------------------------------
__global__ __launch_bounds__(256) void wt_kernel(const float* __restrict__ W,
                                                 u16* __restrict__ WT) {
  __shared__ float tile[32][33];
  int i0 = blockIdx.y * 32;  // k rows of W
  int j0 = blockIdx.x * 32;  // cout cols of W
  int tx = threadIdx.x, ty = threadIdx.y;  // (32, 8)
  for (int r = ty; r < 32; r += 8)
    tile[r][tx] = W[(size_t)(i0 + r) * CDIM + j0 + tx];
  __syncthreads();
  for (int r = ty; r < 32; r += 8)
    WT[(size_t)(j0 + r) * CDIM + i0 + tx] = f2bf(tile[tx][r]);
}

// ---------------------------------------------------------------------------
// bf16 MFMA GEMM: C[M, Nt] = A[M, K] * B[Nt, K]^T   (B stored row-major [Nt,K])
// 256 threads = 4 waves in 2x2; BK=32; per-wave sub-tiles of 16x16x32 MFMA.
// MODE 0: write bf16 C[m*Nt + n]
// MODE 1: write bf16 transposed C[n*M + m]
// MODE 2: write fp32 transposed + bf16 residual: C[n*M+m] = acc + Res[m*Nt+n]
// All dims assumed multiples of the tile (true for this problem).
// ---------------------------------------------------------------------------
template <int BM, int BN, int MODE>
__global__ __launch_bounds__(256) void gemm_bt(const u16* __restrict__ Ag,
                                               const u16* __restrict__ Bg,
                                               void* __restrict__ Cg,
                                               const u16* __restrict__ Res,
                                               int M, int Nt, int K,
                                               size_t sA_, size_t sB_, size_t sC_, size_t sR_) {
  constexpr int BK = 32;
  constexpr int TM = BM / 32;   // sub-tiles per wave in m (WM=2)
  constexpr int TN = BN / 32;   // sub-tiles per wave in n (WN=2)
  __shared__ u16 shA[BM][BK + 8];
  __shared__ u16 shB[BN][BK + 8];

  int bz = blockIdx.z;
  const u16* A = Ag + (size_t)bz * sA_;
  const u16* B = Bg + (size_t)bz * sB_;

  int m0 = blockIdx.y * BM;
  int n0 = blockIdx.x * BN;

  int tid  = threadIdx.x;
  int lane = tid & 63;
  int wave = tid >> 6;
  int wm = wave >> 1, wn = wave & 1;
  int col  = lane & 15;
  int quad = lane >> 4;

  f32x4 acc[TM][TN];
#pragma unroll
  for (int i = 0; i < TM; ++i)
#pragma unroll
    for (int j = 0; j < TN; ++j) acc[i][j] = (f32x4){0.f, 0.f, 0.f, 0.f};

  constexpr int ACH = BM * BK / 8;  // 16B chunks in A tile
  constexpr int BCH = BN * BK / 8;

  for (int kb = 0; kb < K; kb += BK) {
    __syncthreads();
#pragma unroll
    for (int c = tid; c < ACH; c += 256) {
      int row = c >> 2, kc = c & 3;
      *(uint4*)&shA[row][kc * 8] = *(const uint4*)&A[(size_t)(m0 + row) * K + kb + kc * 8];
    }
#pragma unroll
    for (int c = tid; c < BCH; c += 256) {
      int row = c >> 2, kc = c & 3;
      *(uint4*)&shB[row][kc * 8] = *(const uint4*)&B[(size_t)(n0 + row) * K + kb + kc * 8];
    }
    __syncthreads();

    bf16x8 af[TM], bfv[TN];
#pragma unroll
    for (int i = 0; i < TM; ++i)
      af[i] = *(const bf16x8*)&shA[wm * (BM / 2) + i * 16 + col][quad * 8];
#pragma unroll
    for (int j = 0; j < TN; ++j)
      bfv[j] = *(const bf16x8*)&shB[wn * (BN / 2) + j * 16 + col][quad * 8];
#pragma unroll
    for (int i = 0; i < TM; ++i)
#pragma unroll
      for (int j = 0; j < TN; ++j)
        acc[i][j] = __builtin_amdgcn_mfma_f32_16x16x32_bf16(af[i], bfv[j], acc[i][j], 0, 0, 0);
  }

  int r0 = quad * 4;
#pragma unroll
  for (int i = 0; i < TM; ++i) {
    int mbase = m0 + wm * (BM / 2) + i * 16 + r0;
#pragma unroll
    for (int j = 0; j < TN; ++j) {
      int n = n0 + wn * (BN / 2) + j * 16 + col;
#pragma unroll
      for (int r = 0; r < 4; ++r) {
        int m = mbase + r;
        float v = acc[i][j][r];
        if (MODE == 0) {
          ((u16*)Cg)[(size_t)bz * sC_ + (size_t)m * Nt + n] = f2bf(v);
        } else if (MODE == 1) {
          ((u16*)Cg)[(size_t)bz * sC_ + (size_t)n * M + m] = f2bf(v);
        } else {
          float res = bf2f(Res[(size_t)bz * sR_ + (size_t)m * Nt + n]);
          ((float*)Cg)[(size_t)bz * sC_ + (size_t)n * M + m] = v + res;
        }
      }
    }
  }
}

// ---------------------------------------------------------------------------
// Row-wise mix: S (bf16, [B*N rows, N cols]) -> a1*softmax(S) + a2*relu(S)^2
// One block (256 thr) per row; 16 elements per thread, vectorized 16B I/O.
// ---------------------------------------------------------------------------
__global__ __launch_bounds__(256) void mix_kernel(u16* __restrict__ S,
                                                  const float* __restrict__ w1p,
                                                  const float* __restrict__ w2p) {
  __shared__ float sred[4];
  __shared__ float ssum[4];
  size_t row = blockIdx.x;
  u16* Sr = S + row * (size_t)NTOK;
  int tid  = threadIdx.x;
  int lane = tid & 63;
  int wave = tid >> 6;

  uint4 c0 = ((const uint4*)Sr)[tid];
  uint4 c1 = ((const uint4*)Sr)[tid + 256];
  float v[16];
  {
    uint32_t w[8] = {c0.x, c0.y, c0.z, c0.w, c1.x, c1.y, c1.z, c1.w};
#pragma unroll
    for (int i = 0; i < 8; ++i) {
      v[2 * i]     = bf2f((u16)(w[i] & 0xffffu));
      v[2 * i + 1] = bf2f((u16)(w[i] >> 16));
    }
  }

  float mx = -1e30f;
#pragma unroll
  for (int i = 0; i < 16; ++i) mx = fmaxf(mx, v[i]);
  for (int off = 1; off < 64; off <<= 1) mx = fmaxf(mx, __shfl_xor(mx, off));
  if (lane == 0) sred[wave] = mx;
  __syncthreads();
  mx = fmaxf(fmaxf(sred[0], sred[1]), fmaxf(sred[2], sred[3]));

  float e[16];
  float s = 0.f;
#pragma unroll
  for (int i = 0; i < 16; ++i) { e[i] = __expf(v[i] - mx); s += e[i]; }
  for (int off = 1; off < 64; off <<= 1) s += __shfl_xor(s, off);
  if (lane == 0) ssum[wave] = s;
  __syncthreads();
  float total = ssum[0] + ssum[1] + ssum[2] + ssum[3];

  float e1 = __expf(w1p[0]), e2 = __expf(w2p[0]);
  float a1 = e1 / (e1 + e2), a2 = e2 / (e1 + e2);
  float inv = a1 / total;

  float o[16];
#pragma unroll
  for (int i = 0; i < 16; ++i) {
    float r = v[i] > 0.f ? v[i] : 0.f;
    o[i] = e[i] * inv + a2 * r * r;
  }
  uint32_t p[8];
#pragma unroll
  for (int i = 0; i < 8; ++i)
    p[i] = (uint32_t)f2bf(o[2 * i]) | ((uint32_t)f2bf(o[2 * i + 1]) << 16);
  uint4 o0 = {p[0], p[1], p[2], p[3]};
  uint4 o1 = {p[4], p[5], p[6], p[7]};
  ((uint4*)Sr)[tid]       = o0;
  ((uint4*)Sr)[tid + 256] = o1;
}

// ---------------------------------------------------------------------------
extern "C" void kernel_launch(void* const* d_in, const int* in_sizes, int n_in,
                              void* d_out, int out_size, void* d_ws, size_t ws_size,
                              hipStream_t stream) {
  const float* x     = (const float*)d_in[0];
  const float* gamma = (const float*)d_in[1];
  const float* beta  = (const float*)d_in[2];
  const float* Wq    = (const float*)d_in[3];
  const float* Wk    = (const float*)d_in[4];
  const float* Wv    = (const float*)d_in[5];
  const float* w1    = (const float*)d_in[6];
  const float* w2    = (const float*)d_in[7];
  float* out = (float*)d_out;

  char* ws = (char*)d_ws;
  size_t off = 0;
  u16* xn  = (u16*)(ws + off); off += (size_t)BATCH * NTOK * CDIM * 2;   // 8 MB
  u16* WqT = (u16*)(ws + off); off += (size_t)CDIM * CDIM * 2;
  u16* WkT = (u16*)(ws + off); off += (size_t)CDIM * CDIM * 2;
  u16* WvT = (u16*)(ws + off); off += (size_t)CDIM * CDIM * 2;
  u16* Qb  = (u16*)(ws + off); off += (size_t)BATCH * NTOK * CDIM * 2;   // 8 MB
  u16* Kb  = (u16*)(ws + off); off += (size_t)BATCH * NTOK * CDIM * 2;   // 8 MB
  u16* VT  = (u16*)(ws + off); off += (size_t)BATCH * NTOK * CDIM * 2;   // 8 MB (stored [C][N] per batch)
  u16* S   = (u16*)(ws + off); off += (size_t)BATCH * NTOK * NTOK * 2;   // 128 MB
  // total ~161 MB of d_ws

  // 1) LayerNorm -> xn bf16 [B*N, C]
  ln_kernel<<<dim3(BATCH * (NTOK / 32)), 256, 0, stream>>>(x, gamma, beta, xn);

  // 2) W transposes -> bf16 [Cout, K]
  wt_kernel<<<dim3(8, 8), dim3(32, 8), 0, stream>>>(Wq, WqT);
  wt_kernel<<<dim3(8, 8), dim3(32, 8), 0, stream>>>(Wk, WkT);
  wt_kernel<<<dim3(8, 8), dim3(32, 8), 0, stream>>>(Wv, WvT);

  // 3) Q = xn @ WqT^T, K = xn @ WkT^T   (M = B*N = 16384 all batches at once)
  gemm_bt<128, 64, 0><<<dim3(4, 128, 1), 256, 0, stream>>>(
      xn, WqT, Qb, nullptr, BATCH * NTOK, CDIM, CDIM, 0, 0, 0, 0);
  gemm_bt<128, 64, 0><<<dim3(4, 128, 1), 256, 0, stream>>>(
      xn, WkT, Kb, nullptr, BATCH * NTOK, CDIM, CDIM, 0, 0, 0, 0);
  // V, written transposed per batch: VT[b][c][n]
  gemm_bt<128, 64, 1><<<dim3(4, 32, BATCH), 256, 0, stream>>>(
      xn, WvT, VT, nullptr, NTOK, CDIM, CDIM,
      (size_t)NTOK * CDIM, 0, (size_t)NTOK * CDIM, 0);

  // 4) S = Q @ K^T per batch -> bf16 [N, N]
  gemm_bt<128, 128, 0><<<dim3(32, 32, BATCH), 256, 0, stream>>>(
      Qb, Kb, S, nullptr, NTOK, NTOK, CDIM,
      (size_t)NTOK * CDIM, (size_t)NTOK * CDIM, (size_t)NTOK * NTOK, 0);

  // 5) mix: S <- a1*softmax(S) + a2*relu(S)^2, in place
  mix_kernel<<<dim3(BATCH * NTOK), 256, 0, stream>>>(S, w1, w2);

  // 6) out[b][c][n] = (attn @ V)[n][c] + xn[n][c]   (transposed write + residual)
  gemm_bt<128, 64, 2><<<dim3(4, 32, BATCH), 256, 0, stream>>>(
      S, VT, out, xn, NTOK, CDIM, NTOK,
      (size_t)NTOK * NTOK, (size_t)NTOK * CDIM, (size_t)NTOK * CDIM, (size_t)NTOK * CDIM);
}

// Round 2
// 390.502 us; speedup vs baseline: 1.0399x; 1.0399x over previous
//
#include <hip/hip_runtime.h>
#include <hip/hip_bf16.h>
#include <cstdint>

typedef unsigned short u16;
typedef __attribute__((ext_vector_type(8))) short bf16x8;
typedef __attribute__((ext_vector_type(4))) float f32x4;

#define BATCH 4
#define CDIM 256
#define NTOK 4096   // H*W

__device__ inline u16 f2bf(float f) {
  union { float f; uint32_t u; } un; un.f = f;
  uint32_t u = un.u;
  u += 0x7fffu + ((u >> 16) & 1u);
  return (u16)(u >> 16);
}
__device__ inline float bf2f(u16 h) {
  union { uint32_t u; float f; } un; un.u = ((uint32_t)h) << 16; return un.f;
}

// ---------------------------------------------------------------------------
// LayerNorm: x [B, C, N] -> xn bf16 [B*N, C]
// ---------------------------------------------------------------------------
__global__ __launch_bounds__(256) void ln_kernel(const float* __restrict__ x,
                                                 const float* __restrict__ gamma,
                                                 const float* __restrict__ beta,
                                                 u16* __restrict__ xn) {
  __shared__ float tile[CDIM][33];
  __shared__ float reds[8][32];
  __shared__ float reds2[8][32];
  __shared__ float mu_s[32], rs_s[32];

  int b  = blockIdx.x >> 7;
  int n0 = (blockIdx.x & 127) * 32;
  const float* xb = x + (size_t)b * CDIM * NTOK;

  int t = threadIdx.x & 31;
  int g = threadIdx.x >> 5;

  for (int c = g; c < CDIM; c += 8)
    tile[c][t] = xb[(size_t)c * NTOK + n0 + t];
  __syncthreads();

  float s = 0.f, s2 = 0.f;
  for (int c = g * 32; c < g * 32 + 32; ++c) {
    float v = tile[c][t];
    s += v; s2 += v * v;
  }
  reds[g][t] = s; reds2[g][t] = s2;
  __syncthreads();
  if (threadIdx.x < 32) {
    float ts = 0.f, ts2 = 0.f;
    for (int gg = 0; gg < 8; ++gg) { ts += reds[gg][threadIdx.x]; ts2 += reds2[gg][threadIdx.x]; }
    float mu = ts / CDIM;
    float var = ts2 / CDIM - mu * mu;
    mu_s[threadIdx.x] = mu;
    rs_s[threadIdx.x] = rsqrtf(var + 1e-5f);
  }
  __syncthreads();

  int c = threadIdx.x;
  float gam = gamma[c], bet = beta[c];
  u16* out = xn + ((size_t)b * NTOK + n0) * CDIM;
  for (int tt = 0; tt < 32; ++tt) {
    float v = tile[c][tt];
    float y = (v - mu_s[tt]) * rs_s[tt] * gam + bet;
    out[(size_t)tt * CDIM + c] = f2bf(y);
  }
}

// ---------------------------------------------------------------------------
// W [K, Cout] fp32 -> WT bf16 [Cout, K]
// ---------------------------------------------------------------------------
__global__ __launch_bounds__(256) void wt_kernel(const float* __restrict__ W,
                                                 u16* __restrict__ WT) {
  __shared__ float tile[32][33];
  int i0 = blockIdx.y * 32;
  int j0 = blockIdx.x * 32;
  int tx = threadIdx.x, ty = threadIdx.y;
  for (int r = ty; r < 32; r += 8)
    tile[r][tx] = W[(size_t)(i0 + r) * CDIM + j0 + tx];
  __syncthreads();
  for (int r = ty; r < 32; r += 8)
    WT[(size_t)(j0 + r) * CDIM + i0 + tx] = f2bf(tile[tx][r]);
}

// ---------------------------------------------------------------------------
// bf16 MFMA GEMM (projections): C = A[M,K] * B[Nt,K]^T
// MODE 0: bf16 row-major; MODE 1: bf16 transposed C[n*M+m]
// ---------------------------------------------------------------------------
template <int BM, int BN, int MODE>
__global__ __launch_bounds__(256) void gemm_bt(const u16* __restrict__ Ag,
                                               const u16* __restrict__ Bg,
                                               void* __restrict__ Cg,
                                               int M, int Nt, int K,
                                               size_t sA_, size_t sB_, size_t sC_) {
  constexpr int BK = 32;
  constexpr int TM = BM / 32;
  constexpr int TN = BN / 32;
  __shared__ u16 shA[BM][BK + 8];
  __shared__ u16 shB[BN][BK + 8];

  int bz = blockIdx.z;
  const u16* A = Ag + (size_t)bz * sA_;
  const u16* B = Bg + (size_t)bz * sB_;

  int m0 = blockIdx.y * BM;
  int n0 = blockIdx.x * BN;

  int tid  = threadIdx.x;
  int lane = tid & 63;
  int wave = tid >> 6;
  int wm = wave >> 1, wn = wave & 1;
  int col  = lane & 15;
  int quad = lane >> 4;

  f32x4 acc[TM][TN];
#pragma unroll
  for (int i = 0; i < TM; ++i)
#pragma unroll
    for (int j = 0; j < TN; ++j) acc[i][j] = (f32x4){0.f, 0.f, 0.f, 0.f};

  constexpr int ACH = BM * BK / 8;
  constexpr int BCH = BN * BK / 8;

  for (int kb = 0; kb < K; kb += BK) {
    __syncthreads();
#pragma unroll
    for (int c = tid; c < ACH; c += 256) {
      int row = c >> 2, kc = c & 3;
      *(uint4*)&shA[row][kc * 8] = *(const uint4*)&A[(size_t)(m0 + row) * K + kb + kc * 8];
    }
#pragma unroll
    for (int c = tid; c < BCH; c += 256) {
      int row = c >> 2, kc = c & 3;
      *(uint4*)&shB[row][kc * 8] = *(const uint4*)&B[(size_t)(n0 + row) * K + kb + kc * 8];
    }
    __syncthreads();

    bf16x8 af[TM], bfv[TN];
#pragma unroll
    for (int i = 0; i < TM; ++i)
      af[i] = *(const bf16x8*)&shA[wm * (BM / 2) + i * 16 + col][quad * 8];
#pragma unroll
    for (int j = 0; j < TN; ++j)
      bfv[j] = *(const bf16x8*)&shB[wn * (BN / 2) + j * 16 + col][quad * 8];
#pragma unroll
    for (int i = 0; i < TM; ++i)
#pragma unroll
      for (int j = 0; j < TN; ++j)
        acc[i][j] = __builtin_amdgcn_mfma_f32_16x16x32_bf16(af[i], bfv[j], acc[i][j], 0, 0, 0);
  }

  int r0 = quad * 4;
#pragma unroll
  for (int i = 0; i < TM; ++i) {
    int mbase = m0 + wm * (BM / 2) + i * 16 + r0;
#pragma unroll
    for (int j = 0; j < TN; ++j) {
      int n = n0 + wn * (BN / 2) + j * 16 + col;
#pragma unroll
      for (int r = 0; r < 4; ++r) {
        int m = mbase + r;
        float v = acc[i][j][r];
        if (MODE == 0) {
          ((u16*)Cg)[(size_t)bz * sC_ + (size_t)m * Nt + n] = f2bf(v);
        } else {
          ((u16*)Cg)[(size_t)bz * sC_ + (size_t)n * M + m] = f2bf(v);
        }
      }
    }
  }
}

// ---------------------------------------------------------------------------
// Fused flash-style attention with mixed softmax/relu^2 weighting.
// Per block: 64 Q rows, iterate KV in tiles of 64.
//   S = Q K^T (MFMA)  ->  online m,l  ->  P1=exp(S-m), P2=relu(S)^2 (LDS)
//   O1 += P1 V (rescaled by alpha), O2 += P2 V
// Epilogue: out[b][c][n] = a1*O1/l + a2*O2 + xn[n][c]  (LDS transpose)
// Block = 256 thr (4 waves, 2x2). LDS ~104KB -> 1 block/CU.
// ---------------------------------------------------------------------------
#define QK_LD 264   // u16 stride for Q/K tiles (256+8)
#define PV_LD 72    // u16 stride for P / V^T tiles (64+8)

__global__ __launch_bounds__(256, 1) void fa_kernel(const u16* __restrict__ Qg,
                                                    const u16* __restrict__ Kg,
                                                    const u16* __restrict__ Vtg,
                                                    const u16* __restrict__ xng,
                                                    const float* __restrict__ w1p,
                                                    const float* __restrict__ w2p,
                                                    float* __restrict__ outg) {
  __shared__ __align__(16) char smem[105984];
  u16* Qs = (u16*)smem;                       // [64][264]  33792 B
  u16* Ks = (u16*)(smem + 33792);             // [64][264]  33792 B (P1/P2 overlay)
  u16* P1 = (u16*)(smem + 33792);             // [64][72]
  u16* P2 = P1 + 64 * PV_LD;                  // [64][72]
  u16* Vs = (u16*)(smem + 67584);             // [256][72]  36864 B
  float* mrow = (float*)(smem + 104448);      // [64]
  float* lrow = mrow + 64;                    // [64]
  float* pmax = mrow + 128;                   // [2][64]
  float* psum = mrow + 256;                   // [2][64]
  float* otile = (float*)smem;                // epilogue [256][68] = 69632 B

  int lin = blockIdx.x;
  int b = lin & 3;                 // XCD swizzle: same XCD -> same batch
  int q0 = (lin >> 2) * 64;

  const u16* Q  = Qg  + (size_t)b * NTOK * CDIM;
  const u16* K  = Kg  + (size_t)b * NTOK * CDIM;
  const u16* Vt = Vtg + (size_t)b * NTOK * CDIM;

  int tid  = threadIdx.x;
  int lane = tid & 63;
  int wave = tid >> 6;
  int wm = wave >> 1, wn = wave & 1;
  int col = lane & 15, quad = lane >> 4;

  // ---- stage Q tile [64][256], init stats ----
  {
    int row = tid >> 5, ch = tid & 31;
#pragma unroll
    for (int it = 0; it < 8; ++it)
      *(uint4*)&Qs[(size_t)(row + it * 8) * QK_LD + ch * 8] =
          *(const uint4*)&Q[(size_t)(q0 + row + it * 8) * CDIM + ch * 8];
  }
  if (tid < 64) { mrow[tid] = -1e30f; lrow[tid] = 0.f; }
  __syncthreads();

  // ---- preload Q A-frags into registers (reused across all 64 tiles) ----
  bf16x8 aq[2][8];
#pragma unroll
  for (int i = 0; i < 2; ++i)
#pragma unroll
    for (int k = 0; k < 8; ++k)
      aq[i][k] = *(const bf16x8*)&Qs[(size_t)(wm * 32 + i * 16 + col) * QK_LD + k * 32 + quad * 8];

  f32x4 o1[2][8], o2[2][8];
#pragma unroll
  for (int i = 0; i < 2; ++i)
#pragma unroll
    for (int j = 0; j < 8; ++j) {
      o1[i][j] = (f32x4){0.f, 0.f, 0.f, 0.f};
      o2[i][j] = (f32x4){0.f, 0.f, 0.f, 0.f};
    }

  for (int n0 = 0; n0 < NTOK; n0 += 64) {
    // ---- stage K tile [64][256] and V^T tile [256][64] ----
    {
      int row = tid >> 5, ch = tid & 31;
#pragma unroll
      for (int it = 0; it < 8; ++it)
        *(uint4*)&Ks[(size_t)(row + it * 8) * QK_LD + ch * 8] =
            *(const uint4*)&K[(size_t)(n0 + row + it * 8) * CDIM + ch * 8];
      int vrow = tid >> 3, vch = tid & 7;
#pragma unroll
      for (int it = 0; it < 8; ++it)
        *(uint4*)&Vs[(size_t)(vrow + it * 32) * PV_LD + vch * 8] =
            *(const uint4*)&Vt[(size_t)(vrow + it * 32) * NTOK + n0 + vch * 8];
    }
    __syncthreads();   // (a) tiles ready

    // ---- S = Q K^T ----
    f32x4 sacc[2][2];
#pragma unroll
    for (int i = 0; i < 2; ++i)
#pragma unroll
      for (int j = 0; j < 2; ++j) sacc[i][j] = (f32x4){0.f, 0.f, 0.f, 0.f};
#pragma unroll
    for (int k = 0; k < 8; ++k) {
      bf16x8 bk[2];
#pragma unroll
      for (int j = 0; j < 2; ++j)
        bk[j] = *(const bf16x8*)&Ks[(size_t)(wn * 32 + j * 16 + col) * QK_LD + k * 32 + quad * 8];
#pragma unroll
      for (int i = 0; i < 2; ++i)
#pragma unroll
        for (int j = 0; j < 2; ++j)
          sacc[i][j] = __builtin_amdgcn_mfma_f32_16x16x32_bf16(aq[i][k], bk[j], sacc[i][j], 0, 0, 0);
    }

    // ---- per-row max of this wave's 32-col chunk ----
    float vmax[8];
#pragma unroll
    for (int i = 0; i < 2; ++i)
#pragma unroll
      for (int r = 0; r < 4; ++r)
        vmax[i * 4 + r] = fmaxf(sacc[i][0][r], sacc[i][1][r]);
#pragma unroll
    for (int off = 1; off < 16; off <<= 1)
#pragma unroll
      for (int s = 0; s < 8; ++s) vmax[s] = fmaxf(vmax[s], __shfl_xor(vmax[s], off));
    if (col == 0) {
#pragma unroll
      for (int i = 0; i < 2; ++i)
#pragma unroll
        for (int r = 0; r < 4; ++r)
          pmax[wn * 64 + wm * 32 + i * 16 + quad * 4 + r] = vmax[i * 4 + r];
    }
    __syncthreads();   // (b) partial maxes visible; K-frag reads done -> P overlay safe

    // ---- m update, alpha, P1/P2, partial sums ----
    float mnew[8], alpha[8], rsum[8];
#pragma unroll
    for (int i = 0; i < 2; ++i)
#pragma unroll
      for (int r = 0; r < 4; ++r) {
        int row = wm * 32 + i * 16 + quad * 4 + r;
        float pm = fmaxf(pmax[row], pmax[64 + row]);
        float mo = mrow[row];
        float mn = fmaxf(mo, pm);
        mnew[i * 4 + r] = mn;
        alpha[i * 4 + r] = __expf(mo - mn);
        rsum[i * 4 + r] = 0.f;
      }
    // rescale O1
#pragma unroll
    for (int i = 0; i < 2; ++i)
#pragma unroll
      for (int j = 0; j < 8; ++j)
#pragma unroll
        for (int r = 0; r < 4; ++r) o1[i][j][r] *= alpha[i * 4 + r];
    // P tiles
#pragma unroll
    for (int i = 0; i < 2; ++i)
#pragma unroll
      for (int j = 0; j < 2; ++j)
#pragma unroll
        for (int r = 0; r < 4; ++r) {
          int row = wm * 32 + i * 16 + quad * 4 + r;
          int cg  = wn * 32 + j * 16 + col;
          float sv = sacc[i][j][r];
          float p1 = __expf(sv - mnew[i * 4 + r]);
          rsum[i * 4 + r] += p1;
          float p2 = sv > 0.f ? sv * sv : 0.f;
          P1[(size_t)row * PV_LD + cg] = f2bf(p1);
          P2[(size_t)row * PV_LD + cg] = f2bf(p2);
        }
#pragma unroll
    for (int off = 1; off < 16; off <<= 1)
#pragma unroll
      for (int s = 0; s < 8; ++s) rsum[s] += __shfl_xor(rsum[s], off);
    if (col == 0) {
#pragma unroll
      for (int i = 0; i < 2; ++i)
#pragma unroll
        for (int r = 0; r < 4; ++r)
          psum[wn * 64 + wm * 32 + i * 16 + quad * 4 + r] = rsum[i * 4 + r];
    }
    __syncthreads();   // (c) P + psum ready

    // ---- l, m bookkeeping (one lane per row) ----
    if (wn == 0 && col == 0) {
#pragma unroll
      for (int i = 0; i < 2; ++i)
#pragma unroll
        for (int r = 0; r < 4; ++r) {
          int row = wm * 32 + i * 16 + quad * 4 + r;
          lrow[row] = lrow[row] * alpha[i * 4 + r] + psum[row] + psum[64 + row];
          mrow[row] = mnew[i * 4 + r];
        }
    }

    // ---- O1 += P1 V, O2 += P2 V ----
#pragma unroll
    for (int k2 = 0; k2 < 2; ++k2) {
      bf16x8 pa1[2], pa2[2];
#pragma unroll
      for (int i = 0; i < 2; ++i) {
        pa1[i] = *(const bf16x8*)&P1[(size_t)(wm * 32 + i * 16 + col) * PV_LD + k2 * 32 + quad * 8];
        pa2[i] = *(const bf16x8*)&P2[(size_t)(wm * 32 + i * 16 + col) * PV_LD + k2 * 32 + quad * 8];
      }
#pragma unroll
      for (int j = 0; j < 8; ++j) {
        bf16x8 bv = *(const bf16x8*)&Vs[(size_t)(wn * 128 + j * 16 + col) * PV_LD + k2 * 32 + quad * 8];
#pragma unroll
        for (int i = 0; i < 2; ++i) {
          o1[i][j] = __builtin_amdgcn_mfma_f32_16x16x32_bf16(pa1[i], bv, o1[i][j], 0, 0, 0);
          o2[i][j] = __builtin_amdgcn_mfma_f32_16x16x32_bf16(pa2[i], bv, o2[i][j], 0, 0, 0);
        }
      }
    }
    __syncthreads();   // (d) P/V reads done -> next staging may overwrite
  }

  // ---- epilogue ----
  float e1 = __expf(w1p[0]), e2 = __expf(w2p[0]);
  float a1 = e1 / (e1 + e2), a2 = e2 / (e1 + e2);
  float linv[8];
#pragma unroll
  for (int i = 0; i < 2; ++i)
#pragma unroll
    for (int r = 0; r < 4; ++r)
      linv[i * 4 + r] = a1 / lrow[wm * 32 + i * 16 + quad * 4 + r];

#pragma unroll
  for (int i = 0; i < 2; ++i)
#pragma unroll
    for (int j = 0; j < 8; ++j)
#pragma unroll
      for (int r = 0; r < 4; ++r) {
        int row = wm * 32 + i * 16 + quad * 4 + r;       // local n
        int c   = wn * 128 + j * 16 + col;
        float v = o1[i][j][r] * linv[i * 4 + r] + a2 * o2[i][j][r];
        v += bf2f(xng[((size_t)b * NTOK + q0 + row) * CDIM + c]);
        otile[(size_t)c * 68 + row] = v;
      }
  __syncthreads();

#pragma unroll
  for (int it = 0; it < 16; ++it) {
    int c  = it * 16 + (tid >> 4);
    int ch = tid & 15;
    *(float4*)&outg[((size_t)b * CDIM + c) * NTOK + q0 + ch * 4] =
        *(const float4*)&otile[(size_t)c * 68 + ch * 4];
  }
}

// ---------------------------------------------------------------------------
extern "C" void kernel_launch(void* const* d_in, const int* in_sizes, int n_in,
                              void* d_out, int out_size, void* d_ws, size_t ws_size,
                              hipStream_t stream) {
  const float* x     = (const float*)d_in[0];
  const float* gamma = (const float*)d_in[1];
  const float* beta  = (const float*)d_in[2];
  const float* Wq    = (const float*)d_in[3];
  const float* Wk    = (const float*)d_in[4];
  const float* Wv    = (const float*)d_in[5];
  const float* w1    = (const float*)d_in[6];
  const float* w2    = (const float*)d_in[7];
  float* out = (float*)d_out;

  char* ws = (char*)d_ws;
  size_t off = 0;
  u16* xn  = (u16*)(ws + off); off += (size_t)BATCH * NTOK * CDIM * 2;
  u16* WqT = (u16*)(ws + off); off += (size_t)CDIM * CDIM * 2;
  u16* WkT = (u16*)(ws + off); off += (size_t)CDIM * CDIM * 2;
  u16* WvT = (u16*)(ws + off); off += (size_t)CDIM * CDIM * 2;
  u16* Qb  = (u16*)(ws + off); off += (size_t)BATCH * NTOK * CDIM * 2;
  u16* Kb  = (u16*)(ws + off); off += (size_t)BATCH * NTOK * CDIM * 2;
  u16* VT  = (u16*)(ws + off); off += (size_t)BATCH * NTOK * CDIM * 2;  // [b][c][n]

  // 1) LayerNorm -> xn bf16 [B*N, C]
  ln_kernel<<<dim3(BATCH * (NTOK / 32)), 256, 0, stream>>>(x, gamma, beta, xn);

  // 2) weight transposes
  wt_kernel<<<dim3(8, 8), dim3(32, 8), 0, stream>>>(Wq, WqT);
  wt_kernel<<<dim3(8, 8), dim3(32, 8), 0, stream>>>(Wk, WkT);
  wt_kernel<<<dim3(8, 8), dim3(32, 8), 0, stream>>>(Wv, WvT);

  // 3) projections
  gemm_bt<128, 64, 0><<<dim3(4, 128, 1), 256, 0, stream>>>(
      xn, WqT, Qb, BATCH * NTOK, CDIM, CDIM, 0, 0, 0);
  gemm_bt<128, 64, 0><<<dim3(4, 128, 1), 256, 0, stream>>>(
      xn, WkT, Kb, BATCH * NTOK, CDIM, CDIM, 0, 0, 0);
  gemm_bt<128, 64, 1><<<dim3(4, 32, BATCH), 256, 0, stream>>>(
      xn, WvT, VT, NTOK, CDIM, CDIM,
      (size_t)NTOK * CDIM, 0, (size_t)NTOK * CDIM);

  // 4) fused attention + mix + residual + transpose
  fa_kernel<<<dim3(256), 256, 0, stream>>>(Qb, Kb, VT, xn, w1, w2, out);
}